// Round 3
// baseline (361.666 us; speedup 1.0000x reference)
//
#include <hip/hip_runtime.h>
#include <hip/hip_bf16.h>

#define NUM_FIELDS 39
#define PER_FIELD_VOCAB 10000
#define EMBED_DIM 128
#define KPAD 64          // F padded to 64: two K=32 chunks for mfma_f32_16x16x32_bf16
#define NL 5             // 2 (W0) + 3 (W1) interaction slabs
#define RANK 128
#define BATCH 2048

typedef __bf16  bf16x8  __attribute__((ext_vector_type(8)));
typedef float   f32x4   __attribute__((ext_vector_type(4)));
typedef float   f32x4u  __attribute__((ext_vector_type(4), aligned(4)));  // 4B-aligned vec
typedef float   f32x2u  __attribute__((ext_vector_type(2), aligned(4)));

// ---------------------------------------------------------------------------
// Single fused kernel: one workgroup (256 thr = 4 waves) per batch element.
//   ret[b] = bias + sum_f linear[idx] + sum_{r,d} dp0*dp1 + sum_{r,d} dp2*dp3*dp4
//   dp_l[r,d] = sum_f W[l,r,f] * emb[b,f,d]   via mfma_f32_16x16x32_bf16, K=64
//
// prep_w is gone: W0/W1 are ~100 KB f32 and L2-hot (every block reads them),
// so each thread builds its A-fragments directly with cvt_pk — this removes a
// dispatch + graph gap + the Wb HBM round trip from the serial critical path.
//
// eT[d][f] bf16, stride 64 elems (128 B), XOR-swizzled:
//   byte = d*128 + (col_byte ^ ((d&7)<<4))
// Same formula on write and read (both-sides-or-neither); bijective since the
// row stride is a multiple of 128 B. Write: b128 per (f8,d) unit, 8 distinct
// 16B columns per 8 consecutive d -> conflict-free. Read: 2-way max (free).
//
// Correctness: only sum_k and sum over all (r,d) are needed, and all 5 accs
// share one C/D layout with identical (r,d) pairing, so the product fold is
// layout-agnostic. A/B use the same per-lane k-order (quad*8+j within chunk).
// ---------------------------------------------------------------------------
__global__ __launch_bounds__(256) void tfm_main(const int* __restrict__ x,
                                                const float* __restrict__ embed_table,
                                                const float* __restrict__ linear_table,
                                                const float* __restrict__ bias,
                                                const float* __restrict__ W0,
                                                const float* __restrict__ W1,
                                                float* __restrict__ out,
                                                int out_size) {
    __shared__ int   sidx[NUM_FIELDS];
    __shared__ __align__(16) __bf16 eT[EMBED_DIM * KPAD];   // 16 KB, swizzled
    __shared__ float wpart[4];

    const int tid = threadIdx.x;
    const int b   = blockIdx.x;

    if (tid < NUM_FIELDS)
        sidx[tid] = x[b * NUM_FIELDS + tid] + tid * PER_FIELD_VOCAB;
    __syncthreads();

    // Linear term folded into the per-thread partial before the block reduce.
    float partial = (tid < NUM_FIELDS) ? linear_table[sidx[tid]] : 0.f;

    // Gather -> LDS transpose. Unit u = (f8, d): up to 8 coalesced dword loads
    // (8 field rows, same column d), packed to one b128 LDS write.
    // 8 f8-groups x 128 d = 1024 units = exactly 4 iters of 256 threads.
    // f8 is wave-uniform; f>=39 slots write zeros, which also zero-fills the
    // K-pad rows (f 39..63) -- no separate pad loop.
    char* eTb = (char*)eT;
#pragma unroll
    for (int it = 0; it < 4; ++it) {
        int u  = it * 256 + tid;
        int f8 = u >> 7;                 // 0..7, wave-uniform
        int d  = u & (EMBED_DIM - 1);    // per-lane consecutive -> coalesced
        float v[8];
#pragma unroll
        for (int j = 0; j < 8; ++j) {
            int f = f8 * 8 + j;
            v[j] = (f < NUM_FIELDS) ? embed_table[(long)sidx[f] * EMBED_DIM + d]
                                    : 0.f;
        }
        bf16x8 pk;
#pragma unroll
        for (int j = 0; j < 8; ++j) pk[j] = (__bf16)v[j];
        int off = d * 128 + ((f8 * 16) ^ ((d & 7) << 4));   // byte off, 16B-aligned
        *reinterpret_cast<bf16x8*>(eTb + off) = pk;
    }
    __syncthreads();

    const int wave = tid >> 6, lane = tid & 63;
    const int m = lane & 15, quad = lane >> 4;   // MFMA A/B fragment lane coords

    f32x4 psum = {0.f, 0.f, 0.f, 0.f};

    for (int rti = 0; rti < 2; ++rti) {
        const int r = (wave * 2 + rti) * 16 + m;   // this lane's A row

        // A-fragments straight from W (f32, L2-hot), k-chunk layout matching
        // the eT read: chunk kc holds f = kc*32 + quad*8 + j.
        //   kc=0: f = quad*8 .. +7, all <= 31 < 39  -> full 8-wide load.
        //   kc=1: quad==0 -> f = 32..39, valid 32..38 (4+2+1 loads, j=7 zero);
        //         quad>=1 -> f >= 40, all zero.
        bf16x8 afrag[NL][2];
#pragma unroll
        for (int l = 0; l < NL; ++l) {
            const float* Wrow = (l < 2)
                ? W0 + (size_t)(l * RANK + r) * NUM_FIELDS
                : W1 + (size_t)((l - 2) * RANK + r) * NUM_FIELDS;
            f32x4u wa = *reinterpret_cast<const f32x4u*>(Wrow + quad * 8);
            f32x4u wb = *reinterpret_cast<const f32x4u*>(Wrow + quad * 8 + 4);
            bf16x8 A0;
#pragma unroll
            for (int j = 0; j < 4; ++j) { A0[j] = (__bf16)wa[j]; A0[4 + j] = (__bf16)wb[j]; }
            afrag[l][0] = A0;

            bf16x8 A1;
            if (quad == 0) {
                f32x4u wc = *reinterpret_cast<const f32x4u*>(Wrow + 32);
                f32x2u wd = *reinterpret_cast<const f32x2u*>(Wrow + 36);
                float  we = Wrow[38];
                A1[0] = (__bf16)wc[0]; A1[1] = (__bf16)wc[1];
                A1[2] = (__bf16)wc[2]; A1[3] = (__bf16)wc[3];
                A1[4] = (__bf16)wd[0]; A1[5] = (__bf16)wd[1];
                A1[6] = (__bf16)we;    A1[7] = (__bf16)0.f;
            } else {
#pragma unroll
                for (int j = 0; j < 8; ++j) A1[j] = (__bf16)0.f;
            }
            afrag[l][1] = A1;
        }

        for (int dt = 0; dt < 8; ++dt) {
            const int row = dt * 16 + m;         // B row index = d; row&7 == m&7
            bf16x8 bfrag[2];
#pragma unroll
            for (int kc = 0; kc < 2; ++kc) {
                int off = row * 128 + ((kc * 64 + quad * 16) ^ ((m & 7) << 4));
                bfrag[kc] = *reinterpret_cast<const bf16x8*>(eTb + off);
            }

            f32x4 acc[NL];
#pragma unroll
            for (int l = 0; l < NL; ++l) {
                acc[l] = (f32x4){0.f, 0.f, 0.f, 0.f};
#pragma unroll
                for (int kc = 0; kc < 2; ++kc)
                    acc[l] = __builtin_amdgcn_mfma_f32_16x16x32_bf16(
                        afrag[l][kc], bfrag[kc], acc[l], 0, 0, 0);
            }
            // dp0*dp1 (W0 pair) + dp2*dp3*dp4 (W1 triple), elementwise in (r,d).
            psum += acc[0] * acc[1] + acc[2] * acc[3] * acc[4];
        }
    }

    partial += psum[0] + psum[1] + psum[2] + psum[3];

    // Block reduction: wave shuffle -> LDS -> thread 0.
#pragma unroll
    for (int off = 32; off > 0; off >>= 1)
        partial += __shfl_down(partial, off, 64);
    if (lane == 0) wpart[wave] = partial;
    __syncthreads();
    if (tid == 0)
        out[b] = wpart[0] + wpart[1] + wpart[2] + wpart[3] + bias[0];

    // Second tuple output ("0") and any trailing pad.
    if (b == 0)
        for (int j = BATCH + tid; j < out_size; j += 256)
            out[j] = 0.f;
}

extern "C" void kernel_launch(void* const* d_in, const int* in_sizes, int n_in,
                              void* d_out, int out_size, void* d_ws, size_t ws_size,
                              hipStream_t stream) {
    const int*   x            = (const int*)d_in[0];
    const float* embed_table  = (const float*)d_in[1];
    const float* linear_table = (const float*)d_in[2];
    const float* bias         = (const float*)d_in[3];
    const float* W0           = (const float*)d_in[4];
    const float* W1           = (const float*)d_in[5];
    (void)d_ws; (void)ws_size;   // workspace no longer needed

    tfm_main<<<BATCH, 256, 0, stream>>>(x, embed_table, linear_table, bias,
                                        W0, W1, (float*)d_out, out_size);
}

// Round 4
// 301.077 us; speedup vs baseline: 1.2012x; 1.2012x over previous
//
#include <hip/hip_runtime.h>
#include <hip/hip_bf16.h>

#define NUM_FIELDS 39
#define PER_FIELD_VOCAB 10000
#define EMBED_DIM 128
#define KPAD 64          // F padded to 64: two K=32 chunks for mfma_f32_16x16x32_bf16
#define NL 5             // 2 (W0) + 3 (W1) interaction slabs
#define RANK 128
#define BATCH 2048

typedef __bf16  bf16x8  __attribute__((ext_vector_type(8)));
typedef float   f32x4   __attribute__((ext_vector_type(4)));

// ---------------------------------------------------------------------------
// Precompute: W0 [2,128,39] f32, W1 [3,128,39] f32  ->  Wb [5][128][64] bf16
// (zero-padded in f; re-run every launch since d_ws is re-poisoned)
// ---------------------------------------------------------------------------
__global__ __launch_bounds__(256) void prep_w(const float* __restrict__ W0,
                                              const float* __restrict__ W1,
                                              __bf16* __restrict__ Wb) {
    int i = blockIdx.x * 256 + threadIdx.x;       // 5*128*64 = 40960 total
    if (i >= NL * RANK * KPAD) return;
    int f = i & (KPAD - 1);
    int r = (i >> 6) & (RANK - 1);
    int l = i >> 13;
    float v = 0.f;
    if (f < NUM_FIELDS) {
        if (l < 2) v = W0[(l * RANK + r) * NUM_FIELDS + f];
        else       v = W1[((l - 2) * RANK + r) * NUM_FIELDS + f];
    }
    Wb[i] = (__bf16)v;
}

// ---------------------------------------------------------------------------
// Main: one workgroup (256 thr = 4 waves) per batch element.
//   ret[b] = bias + sum_f linear[idx] + sum_{r,d} dp0*dp1 + sum_{r,d} dp2*dp3*dp4
//   dp_l[r,d] = sum_f W[l,r,f] * emb[b,f,d]   via mfma_f32_16x16x32_bf16, K=64
//
// Latency-bound kernel -> occupancy is everything:
//   __launch_bounds__(256,4) caps VGPR at 128 => 4 blocks (16 waves) per CU.
// No pre-gather barrier: each thread reads its own x values (L1-broadcast of
// the same 39 dwords) so the embed gather issues immediately.
//
// eT[d][f] bf16, stride 64 elems (128 B), XOR-swizzled:
//   byte = d*128 + (col_byte ^ ((d&7)<<4))
// Same formula on write and read (both-sides-or-neither); bijective since the
// row stride is a multiple of 128 B. Write: b128 per (f8,d) unit, conflict-
// free. Read: b128, conflict-free. Verified absmax-identical in r2/r3.
//
// Correctness: only sum_k and sum over all (r,d) are needed; A and B use the
// same per-lane k-order (k = kc*32 + quad*8 + j), and all 5 accs share one
// C/D layout with identical (r,d) pairing, so the product fold is
// layout-agnostic.
// ---------------------------------------------------------------------------
__global__ __launch_bounds__(256, 4) void tfm_main(const int* __restrict__ x,
                                                   const float* __restrict__ embed_table,
                                                   const float* __restrict__ linear_table,
                                                   const float* __restrict__ bias,
                                                   const __bf16* __restrict__ Wb,
                                                   float* __restrict__ out,
                                                   int out_size) {
    __shared__ __align__(16) __bf16 eT[EMBED_DIM * KPAD];   // 16 KB, swizzled
    __shared__ float wpart[4];

    const int tid = threadIdx.x;
    const int b   = blockIdx.x;
    const int* xb = x + b * NUM_FIELDS;

    // Linear term folded into the per-thread partial before the block reduce.
    float partial = 0.f;
    if (tid < NUM_FIELDS)
        partial = linear_table[xb[tid] + tid * PER_FIELD_VOCAB];

    // Gather -> LDS transpose. Unit u = (f8, d): up to 8 coalesced dword loads
    // (8 field rows, same column d), packed to one b128 LDS write.
    // 8 f8-groups x 128 d = 1024 units = exactly 4 iters of 256 threads.
    // f>=39 slots write zeros, which also zero-fills the K-pad rows.
    char* eTb = (char*)eT;
#pragma unroll
    for (int it = 0; it < 4; ++it) {
        int u  = it * 256 + tid;
        int f8 = u >> 7;                 // 0..7, wave-uniform
        int d  = u & (EMBED_DIM - 1);    // per-lane consecutive -> coalesced
        bf16x8 pk;
#pragma unroll
        for (int j = 0; j < 8; ++j) {
            int f = f8 * 8 + j;
            float v = 0.f;
            if (f < NUM_FIELDS)
                v = embed_table[(long)(xb[f] + f * PER_FIELD_VOCAB) * EMBED_DIM + d];
            pk[j] = (__bf16)v;
        }
        int off = d * 128 + ((f8 * 16) ^ ((d & 7) << 4));   // byte off, 16B-aligned
        *reinterpret_cast<bf16x8*>(eTb + off) = pk;
    }
    __syncthreads();

    const int wave = tid >> 6, lane = tid & 63;
    const int m = lane & 15, quad = lane >> 4;   // MFMA A/B fragment lane coords

    f32x4 psum = {0.f, 0.f, 0.f, 0.f};

    for (int rti = 0; rti < 2; ++rti) {
        const int r0 = (wave * 2 + rti) * 16;

        // A-fragments: 10 x b128 from Wb (bf16, L2-hot), 40 VGPR live.
        bf16x8 afrag[NL][2];
#pragma unroll
        for (int l = 0; l < NL; ++l)
#pragma unroll
            for (int kc = 0; kc < 2; ++kc)
                afrag[l][kc] = *reinterpret_cast<const bf16x8*>(
                    &Wb[(size_t)(l * RANK + r0 + m) * KPAD + kc * 32 + quad * 8]);

        for (int dt = 0; dt < 8; ++dt) {
            const int row = dt * 16 + m;         // B row index = d
            bf16x8 bfrag[2];
#pragma unroll
            for (int kc = 0; kc < 2; ++kc) {
                int off = row * 128 + ((kc * 64 + quad * 16) ^ ((row & 7) << 4));
                bfrag[kc] = *reinterpret_cast<const bf16x8*>(eTb + off);
            }

            f32x4 acc[NL];
#pragma unroll
            for (int l = 0; l < NL; ++l) {
                acc[l] = (f32x4){0.f, 0.f, 0.f, 0.f};
#pragma unroll
                for (int kc = 0; kc < 2; ++kc)
                    acc[l] = __builtin_amdgcn_mfma_f32_16x16x32_bf16(
                        afrag[l][kc], bfrag[kc], acc[l], 0, 0, 0);
            }
            // dp0*dp1 (W0 pair) + dp2*dp3*dp4 (W1 triple), elementwise in (r,d).
            psum += acc[0] * acc[1] + acc[2] * acc[3] * acc[4];
        }
    }

    partial += psum[0] + psum[1] + psum[2] + psum[3];

    // Block reduction: wave shuffle -> LDS -> thread 0.
#pragma unroll
    for (int off = 32; off > 0; off >>= 1)
        partial += __shfl_down(partial, off, 64);
    if (lane == 0) wpart[wave] = partial;
    __syncthreads();
    if (tid == 0)
        out[b] = wpart[0] + wpart[1] + wpart[2] + wpart[3] + bias[0];

    // Second tuple output ("0") and any trailing pad.
    if (b == 0)
        for (int j = BATCH + tid; j < out_size; j += 256)
            out[j] = 0.f;
}

extern "C" void kernel_launch(void* const* d_in, const int* in_sizes, int n_in,
                              void* d_out, int out_size, void* d_ws, size_t ws_size,
                              hipStream_t stream) {
    const int*   x            = (const int*)d_in[0];
    const float* embed_table  = (const float*)d_in[1];
    const float* linear_table = (const float*)d_in[2];
    const float* bias         = (const float*)d_in[3];
    const float* W0           = (const float*)d_in[4];
    const float* W1           = (const float*)d_in[5];
    __bf16*      Wb           = (__bf16*)d_ws;   // 40960 * 2 B = 80 KB scratch

    prep_w<<<(NL * RANK * KPAD + 255) / 256, 256, 0, stream>>>(W0, W1, Wb);
    tfm_main<<<BATCH, 256, 0, stream>>>(x, embed_table, linear_table, bias, Wb,
                                        (float*)d_out, out_size);
}

// Round 5
// 299.292 us; speedup vs baseline: 1.2084x; 1.0060x over previous
//
#include <hip/hip_runtime.h>
#include <hip/hip_bf16.h>

#define NUM_FIELDS 39
#define PER_FIELD_VOCAB 10000
#define EMBED_DIM 128
#define KPAD 64          // F padded to 64: two K=32 chunks for mfma_f32_16x16x32_bf16
#define NL 5             // 2 (W0) + 3 (W1) interaction slabs
#define RANK 128
#define BATCH 2048

typedef __bf16  bf16x8  __attribute__((ext_vector_type(8)));
typedef float   f32x4   __attribute__((ext_vector_type(4)));

// ---------------------------------------------------------------------------
// Precompute: W0 [2,128,39] f32, W1 [3,128,39] f32  ->  Wb [5][128][64] bf16
// (zero-padded in f; re-run every launch since d_ws is re-poisoned)
// ---------------------------------------------------------------------------
__global__ __launch_bounds__(256) void prep_w(const float* __restrict__ W0,
                                              const float* __restrict__ W1,
                                              __bf16* __restrict__ Wb) {
    int i = blockIdx.x * 256 + threadIdx.x;       // 5*128*64 = 40960 total
    if (i >= NL * RANK * KPAD) return;
    int f = i & (KPAD - 1);
    int r = (i >> 6) & (RANK - 1);
    int l = i >> 13;
    float v = 0.f;
    if (f < NUM_FIELDS) {
        if (l < 2) v = W0[(l * RANK + r) * NUM_FIELDS + f];
        else       v = W1[((l - 2) * RANK + r) * NUM_FIELDS + f];
    }
    Wb[i] = (__bf16)v;
}

// ---------------------------------------------------------------------------
// Main: one workgroup (256 thr = 4 waves) per batch element.  (r0 structure.)
//   ret[b] = bias + sum_f linear[idx] + sum_{r,d} dp0*dp1 + sum_{r,d} dp2*dp3*dp4
//   dp_l[r,d] = sum_f W[l,r,f] * emb[b,f,d]   via mfma_f32_16x16x32_bf16, K=64
//
// Single change vs the 277.9 µs baseline: the gather now packs 8 fields per
// b128 LDS write into a 128 B-stride XOR-swizzled eT (pad rows zeroed for
// free), replacing 20 scalar ds_write_b16 wave-instrs at 8-way conflict plus
// a 12-iteration pad loop. Layout verified correct (absmax-identical) and
// bank-conflict-free (SQ_LDS_BANK_CONFLICT=0) in rounds 2-4.
//
// eT[d][f] bf16: byte = d*128 + (col_byte ^ ((d&7)<<4)); same formula on
// write and read (both-sides-or-neither), bijective within each 128 B row.
//
// Correctness: only sum_k and the sum over all (r,d) are needed; A and B use
// the same per-lane k-order (k = kc*32 + quad*8 + j), and all 5 accs share
// one C/D layout with identical (r,d) pairing -> product fold layout-agnostic.
// ---------------------------------------------------------------------------
__global__ __launch_bounds__(256) void tfm_main(const int* __restrict__ x,
                                                const float* __restrict__ embed_table,
                                                const float* __restrict__ linear_table,
                                                const float* __restrict__ bias,
                                                const __bf16* __restrict__ Wb,
                                                float* __restrict__ out,
                                                int out_size) {
    __shared__ int   sidx[NUM_FIELDS];
    __shared__ __align__(16) __bf16 eT[EMBED_DIM * KPAD];   // 16 KB, swizzled
    __shared__ float wpart[4];

    const int tid = threadIdx.x;
    const int b   = blockIdx.x;

    if (tid < NUM_FIELDS)
        sidx[tid] = x[b * NUM_FIELDS + tid] + tid * PER_FIELD_VOCAB;
    __syncthreads();

    // Linear term folded into the per-thread partial before the block reduce.
    float partial = (tid < NUM_FIELDS) ? linear_table[sidx[tid]] : 0.f;

    // Gather -> LDS transpose. Unit u = (f8, d): up to 8 coalesced dword loads
    // (8 field rows, same column d), packed to one b128 LDS write.
    // 8 f8-groups x 128 d = 1024 units = exactly 4 iters of 256 threads.
    // f>=39 slots write zeros, which also zero-fills the K-pad rows (f 39..63).
    char* eTb = (char*)eT;
#pragma unroll
    for (int it = 0; it < 4; ++it) {
        int u  = it * 256 + tid;
        int f8 = u >> 7;                 // 0..7, half-wave-uniform
        int d  = u & (EMBED_DIM - 1);    // per-lane consecutive -> coalesced
        bf16x8 pk;
#pragma unroll
        for (int j = 0; j < 8; ++j) {
            int f = f8 * 8 + j;
            float v = 0.f;
            if (f < NUM_FIELDS)
                v = embed_table[(long)sidx[f] * EMBED_DIM + d];
            pk[j] = (__bf16)v;
        }
        int off = d * 128 + ((f8 * 16) ^ ((d & 7) << 4));   // byte off, 16B-aligned
        *reinterpret_cast<bf16x8*>(eTb + off) = pk;
    }
    __syncthreads();

    const int wave = tid >> 6, lane = tid & 63;
    const int m = lane & 15, quad = lane >> 4;   // MFMA A/B fragment lane coords

    f32x4 psum = {0.f, 0.f, 0.f, 0.f};

    // Wave w owns r-tiles {2w, 2w+1}; all 8 d-tiles. 16x16 tiles, K=64.
    for (int rti = 0; rti < 2; ++rti) {
        const int r0 = (wave * 2 + rti) * 16;
        bf16x8 afrag[NL][2];
#pragma unroll
        for (int l = 0; l < NL; ++l)
#pragma unroll
            for (int kc = 0; kc < 2; ++kc)
                afrag[l][kc] = *reinterpret_cast<const bf16x8*>(
                    &Wb[((size_t)(l * RANK) + r0 + m) * KPAD + kc * 32 + quad * 8]);

        for (int dt = 0; dt < 8; ++dt) {
            const int row = dt * 16 + m;         // B row index = d
            bf16x8 bfrag[2];
#pragma unroll
            for (int kc = 0; kc < 2; ++kc) {
                int off = row * 128 + ((kc * 64 + quad * 16) ^ ((row & 7) << 4));
                bfrag[kc] = *reinterpret_cast<const bf16x8*>(eTb + off);
            }

            f32x4 acc[NL];
#pragma unroll
            for (int l = 0; l < NL; ++l) {
                acc[l] = (f32x4){0.f, 0.f, 0.f, 0.f};
#pragma unroll
                for (int kc = 0; kc < 2; ++kc)
                    acc[l] = __builtin_amdgcn_mfma_f32_16x16x32_bf16(
                        afrag[l][kc], bfrag[kc], acc[l], 0, 0, 0);
            }
            // dp0*dp1 (W0 pair) + dp2*dp3*dp4 (W1 triple), elementwise in (r,d).
            psum += acc[0] * acc[1] + acc[2] * acc[3] * acc[4];
        }
    }

    partial += psum[0] + psum[1] + psum[2] + psum[3];

    // Block reduction: wave shuffle -> LDS -> thread 0.
#pragma unroll
    for (int off = 32; off > 0; off >>= 1)
        partial += __shfl_down(partial, off, 64);
    if (lane == 0) wpart[wave] = partial;
    __syncthreads();
    if (tid == 0)
        out[b] = wpart[0] + wpart[1] + wpart[2] + wpart[3] + bias[0];

    // Second tuple output ("0") and any trailing pad.
    if (b == 0)
        for (int j = BATCH + tid; j < out_size; j += 256)
            out[j] = 0.f;
}

extern "C" void kernel_launch(void* const* d_in, const int* in_sizes, int n_in,
                              void* d_out, int out_size, void* d_ws, size_t ws_size,
                              hipStream_t stream) {
    const int*   x            = (const int*)d_in[0];
    const float* embed_table  = (const float*)d_in[1];
    const float* linear_table = (const float*)d_in[2];
    const float* bias         = (const float*)d_in[3];
    const float* W0           = (const float*)d_in[4];
    const float* W1           = (const float*)d_in[5];
    __bf16*      Wb           = (__bf16*)d_ws;   // 40960 * 2 B = 80 KB scratch

    prep_w<<<(NL * RANK * KPAD + 255) / 256, 256, 0, stream>>>(W0, W1, Wb);
    tfm_main<<<BATCH, 256, 0, stream>>>(x, embed_table, linear_table, bias, Wb,
                                        (float*)d_out, out_size);
}

// Round 6
// 278.249 us; speedup vs baseline: 1.2998x; 1.0756x over previous
//
#include <hip/hip_runtime.h>
#include <hip/hip_bf16.h>

#define NUM_FIELDS 39
#define PER_FIELD_VOCAB 10000
#define EMBED_DIM 128
#define KPAD 64          // F padded to 64 for K-chunks of 32
#define NL 5             // 2 (W0) + 3 (W1) interaction slabs
#define RANK 128
#define BATCH 2048
#define LDS_STRIDE 72    // eT row stride in bf16 elems: 64 + 8 pad -> 144 B, 16B-aligned

typedef __bf16  bf16x8  __attribute__((ext_vector_type(8)));
typedef float   f32x4   __attribute__((ext_vector_type(4)));

// ---------------------------------------------------------------------------
// Precompute: W0 [2,128,39] f32, W1 [3,128,39] f32  ->  Wb [5][128][64] bf16
// (zero-padded in f; re-run every launch since d_ws is re-poisoned)
// ---------------------------------------------------------------------------
__global__ __launch_bounds__(256) void prep_w(const float* __restrict__ W0,
                                              const float* __restrict__ W1,
                                              __bf16* __restrict__ Wb) {
    int i = blockIdx.x * 256 + threadIdx.x;       // 5*128*64 = 40960 total
    if (i >= NL * RANK * KPAD) return;
    int f = i & (KPAD - 1);
    int r = (i >> 6) & (RANK - 1);
    int l = i >> 13;
    float v = 0.f;
    if (f < NUM_FIELDS) {
        if (l < 2) v = W0[(l * RANK + r) * NUM_FIELDS + f];
        else       v = W1[((l - 2) * RANK + r) * NUM_FIELDS + f];
    }
    Wb[i] = (__bf16)v;
}

// ---------------------------------------------------------------------------
// Main: one workgroup (256 thr = 4 waves) per batch element.
//   ret[b] = bias + sum_f linear[idx] + sum_{r,d} dp0*dp1 + sum_{r,d} dp2*dp3*dp4
//   dp_l[r,d] = sum_f W[l,r,f] * emb[b,f,d]   via mfma_f32_16x16x32_bf16
//
// NOTE (session r1-r5): five structural variants were A/B-tested against this
// kernel — 32x32x16 MFMA shape (+7 µs), 512-thread block (+5), fused prep_w
// with f32 A-builds (VGPR 204, +81), __launch_bounds__(256,4) + direct x
// reads (+20), b128 packed swizzled gather (+21, single-variable). All
// regressed; this structure is the measured optimum. The scalar gather wins
// because its 20 independent loads pipeline deeper than packed 8-load units,
// and stride-72 rows give a conflict-acceptable read layout (bank base
// 4*m mod 32). Do not "vectorize" the gather or cap occupancy.
// ---------------------------------------------------------------------------
__global__ __launch_bounds__(256) void tfm_main(const int* __restrict__ x,
                                                const float* __restrict__ embed_table,
                                                const float* __restrict__ linear_table,
                                                const float* __restrict__ bias,
                                                const __bf16* __restrict__ Wb,
                                                float* __restrict__ out,
                                                int out_size) {
    __shared__ int   sidx[NUM_FIELDS];
    __shared__ __align__(16) __bf16 eT[EMBED_DIM * LDS_STRIDE];  // eT[d][f], 18432 B
    __shared__ float wpart[4];

    const int tid = threadIdx.x;
    const int b   = blockIdx.x;

    if (tid < NUM_FIELDS)
        sidx[tid] = x[b * NUM_FIELDS + tid] + tid * PER_FIELD_VOCAB;
    __syncthreads();

    // Gather emb rows -> LDS transposed bf16. Wave reads 64 consecutive d (coalesced 256B).
    for (int k = tid; k < NUM_FIELDS * EMBED_DIM; k += 256) {
        int f = k >> 7, d = k & (EMBED_DIM - 1);
        float v = embed_table[(long)sidx[f] * EMBED_DIM + d];
        eT[d * LDS_STRIDE + f] = (__bf16)v;
    }
    // Zero the K-pad rows f in [39,64) so MFMA pad contributes exactly 0 (no NaN risk).
    for (int k = tid; k < (KPAD - NUM_FIELDS) * EMBED_DIM; k += 256) {
        int f = NUM_FIELDS + (k >> 7), d = k & (EMBED_DIM - 1);
        eT[d * LDS_STRIDE + f] = (__bf16)0.f;
    }

    // Linear term folded into the per-thread partial before the block reduce.
    float partial = 0.f;
    if (tid < NUM_FIELDS) partial = linear_table[sidx[tid]];

    __syncthreads();

    const int wave = tid >> 6, lane = tid & 63;
    const int m = lane & 15, quad = lane >> 4;   // MFMA A/B fragment lane coords

    // Wave w owns r-tiles {2w, 2w+1}; all 8 d-tiles. 16x16 tiles, K=64 (2 chunks of 32).
    for (int rti = 0; rti < 2; ++rti) {
        const int r0 = (wave * 2 + rti) * 16;
        bf16x8 afrag[NL][2];
#pragma unroll
        for (int l = 0; l < NL; ++l)
#pragma unroll
            for (int kc = 0; kc < 2; ++kc)
                afrag[l][kc] = *reinterpret_cast<const bf16x8*>(
                    &Wb[((size_t)(l * RANK) + r0 + m) * KPAD + kc * 32 + quad * 8]);

        for (int dt = 0; dt < 8; ++dt) {
            const int d0 = dt * 16;
            bf16x8 bfrag[2];
#pragma unroll
            for (int kc = 0; kc < 2; ++kc)
                bfrag[kc] = *reinterpret_cast<const bf16x8*>(
                    &eT[(d0 + m) * LDS_STRIDE + kc * 32 + quad * 8]);

            f32x4 acc[NL];
#pragma unroll
            for (int l = 0; l < NL; ++l) {
                acc[l] = (f32x4){0.f, 0.f, 0.f, 0.f};
#pragma unroll
                for (int kc = 0; kc < 2; ++kc)
                    acc[l] = __builtin_amdgcn_mfma_f32_16x16x32_bf16(
                        afrag[l][kc], bfrag[kc], acc[l], 0, 0, 0);
            }
            // dp0*dp1 (W0 pair) + dp2*dp3*dp4 (W1 triple): same C/D layout in all accs,
            // and we reduce over ALL (r,d), so the epilogue is layout-agnostic.
#pragma unroll
            for (int i = 0; i < 4; ++i)
                partial += acc[0][i] * acc[1][i] + acc[2][i] * acc[3][i] * acc[4][i];
        }
    }

    // Block reduction: wave shuffle -> LDS -> thread 0.
#pragma unroll
    for (int off = 32; off > 0; off >>= 1)
        partial += __shfl_down(partial, off, 64);
    if (lane == 0) wpart[wave] = partial;
    __syncthreads();
    if (tid == 0)
        out[b] = wpart[0] + wpart[1] + wpart[2] + wpart[3] + bias[0];

    // Second tuple output ("0") and any trailing pad.
    if (b == 0)
        for (int j = BATCH + tid; j < out_size; j += 256)
            out[j] = 0.f;
}

extern "C" void kernel_launch(void* const* d_in, const int* in_sizes, int n_in,
                              void* d_out, int out_size, void* d_ws, size_t ws_size,
                              hipStream_t stream) {
    const int*   x            = (const int*)d_in[0];
    const float* embed_table  = (const float*)d_in[1];
    const float* linear_table = (const float*)d_in[2];
    const float* bias         = (const float*)d_in[3];
    const float* W0           = (const float*)d_in[4];
    const float* W1           = (const float*)d_in[5];
    __bf16*      Wb           = (__bf16*)d_ws;   // 40960 * 2 B = 80 KB scratch

    prep_w<<<(NL * RANK * KPAD + 255) / 256, 256, 0, stream>>>(W0, W1, Wb);
    tfm_main<<<BATCH, 256, 0, stream>>>(x, embed_table, linear_table, bias, Wb,
                                        (float*)d_out, out_size);
}